// Round 2
// baseline (1885.851 us; speedup 1.0000x reference)
//
#include <hip/hip_runtime.h>
#include <cstdint>
#include <cstddef>

typedef __attribute__((ext_vector_type(8))) short short8;
typedef __attribute__((ext_vector_type(4))) float f32x4;
typedef unsigned short u16;
typedef unsigned int u32;
typedef unsigned long long u64;

__device__ __forceinline__ u16 f2bf(float f) {
    u32 u = __float_as_uint(f);
    u = (u + 0x7FFFu + ((u >> 16) & 1u)) >> 16;
    return (u16)u;
}

#define GLD_LDS16(gsrc, ldst)                                                     \
    __builtin_amdgcn_global_load_lds(                                             \
        (const __attribute__((address_space(1))) u32*)(gsrc),                     \
        (__attribute__((address_space(3))) u32*)(ldst), 16, 0, 0)

// ---------------------------------------------------------------------------
// Elementwise cast fp32 -> bf16 (vectorized x4). n must be multiple of 4.
__global__ void cast_bf16_kernel(const float* __restrict__ src, u16* __restrict__ dst) {
    int i = blockIdx.x * 256 + threadIdx.x;
    float4 v = *((const float4*)src + i);
    ushort4 r;
    r.x = f2bf(v.x); r.y = f2bf(v.y); r.z = f2bf(v.z); r.w = f2bf(v.w);
    *((ushort4*)dst + i) = r;
}

// ---------------------------------------------------------------------------
// Tiled transpose: src fp32 [R][C] -> dst bf16 [C][R]. grid=(C/32, R/32), block=256.
__global__ void cast_transpose_kernel(const float* __restrict__ src, u16* __restrict__ dst,
                                      int R, int C) {
    __shared__ float tile[32][33];
    int tx = threadIdx.x & 31, ty = threadIdx.x >> 5;
    int c0 = blockIdx.x * 32, r0 = blockIdx.y * 32;
#pragma unroll
    for (int j = 0; j < 4; j++)
        tile[ty + 8 * j][tx] = src[(size_t)(r0 + ty + 8 * j) * C + c0 + tx];
    __syncthreads();
#pragma unroll
    for (int j = 0; j < 4; j++)
        dst[(size_t)(c0 + ty + 8 * j) * R + r0 + tx] = f2bf(tile[tx][ty + 8 * j]);
}

// Tiled transpose: src fp32 [R][C] -> dst fp32 [C][R].
__global__ void transpose_f32_kernel(const float* __restrict__ src, float* __restrict__ dst,
                                     int R, int C) {
    __shared__ float tile[32][33];
    int tx = threadIdx.x & 31, ty = threadIdx.x >> 5;
    int c0 = blockIdx.x * 32, r0 = blockIdx.y * 32;
#pragma unroll
    for (int j = 0; j < 4; j++)
        tile[ty + 8 * j][tx] = src[(size_t)(r0 + ty + 8 * j) * C + c0 + tx];
    __syncthreads();
#pragma unroll
    for (int j = 0; j < 4; j++)
        dst[(size_t)(c0 + ty + 8 * j) * R + r0 + tx] = tile[tx][ty + 8 * j];
}

// ---------------------------------------------------------------------------
// mem_keys -> mn (fp32 row-normalized, for argmax) and Kb (bf16 raw, for attention)
__global__ __launch_bounds__(256) void key_prep_kernel(const float* __restrict__ mk,
                                                       float* __restrict__ mn,
                                                       u16* __restrict__ Kb) {
    int row = blockIdx.x, tid = threadIdx.x;
    const float* src = mk + (size_t)row * 512;
    float x0 = src[tid], x1 = src[tid + 256];
    float ss = x0 * x0 + x1 * x1;
#pragma unroll
    for (int m = 1; m < 64; m <<= 1) ss += __shfl_xor(ss, m);
    __shared__ float sred[4];
    if ((tid & 63) == 0) sred[tid >> 6] = ss;
    __syncthreads();
    float tot = sred[0] + sred[1] + sred[2] + sred[3];
    float inv = 1.0f / fmaxf(sqrtf(tot), 1e-8f);
    mn[(size_t)row * 512 + tid] = x0 * inv;
    mn[(size_t)row * 512 + tid + 256] = x1 * inv;
    Kb[(size_t)row * 512 + tid] = f2bf(x0);
    Kb[(size_t)row * 512 + tid + 256] = f2bf(x1);
}

// ---------------------------------------------------------------------------
// GEMM: C[M,N] = A[M,K] * Bt[N,K]^T + bias[N].  bf16 inputs, fp32 accumulate.
// BM=128 fixed, BN template (128 or 64). block=256 (4 waves, 2x2 quadrants).
// EPI==0: write fp32 C row-major [M,N].
// EPI==1: q-proj permute into K-major fragment layout:
//   row=(b*1024+n), col=(h*512+d) -> Qatt2[((b*8+h)*64 + (d>>3))*1024 + n)*8 + (d&7)]
template <int BN, int EPI>
__global__ __launch_bounds__(256, 2) void gemm_bt_kernel(const u16* __restrict__ A,
                                                         const u16* __restrict__ Bt,
                                                         const float* __restrict__ bias,
                                                         void* __restrict__ Cout,
                                                         int M, int N, int K) {
    constexpr int NT = BN / 32;
    __shared__ __align__(16) u16 A_lds[128 * 40];
    __shared__ __align__(16) u16 B_lds[BN * 40];
    int tid = threadIdx.x;
    int w = tid >> 6, lane = tid & 63, l15 = lane & 15, quad = lane >> 4;
    int wm = w >> 1, wn = w & 1;
    int n0 = blockIdx.x * BN, m0 = blockIdx.y * 128;

    f32x4 acc[4][NT];
#pragma unroll
    for (int i = 0; i < 4; i++)
#pragma unroll
        for (int j = 0; j < NT; j++) acc[i][j] = (f32x4)(0.0f);

    for (int kt = 0; kt < K; kt += 32) {
        __syncthreads();
#pragma unroll
        for (int i = 0; i < 2; i++) {
            int c = i * 256 + tid;
            int r = c >> 2, col = c & 3;
            *(uint4*)&A_lds[r * 40 + col * 8] =
                *(const uint4*)&A[(size_t)(m0 + r) * K + kt + col * 8];
        }
#pragma unroll
        for (int i = 0; i < BN / 64; i++) {
            int c = i * 256 + tid;
            int r = c >> 2, col = c & 3;
            *(uint4*)&B_lds[r * 40 + col * 8] =
                *(const uint4*)&Bt[(size_t)(n0 + r) * K + kt + col * 8];
        }
        __syncthreads();
        short8 af[4], bf[NT];
#pragma unroll
        for (int mt = 0; mt < 4; mt++)
            af[mt] = *(const short8*)&A_lds[(wm * 64 + mt * 16 + l15) * 40 + quad * 8];
#pragma unroll
        for (int nt = 0; nt < NT; nt++)
            bf[nt] = *(const short8*)&B_lds[(wn * (BN / 2) + nt * 16 + l15) * 40 + quad * 8];
#pragma unroll
        for (int mt = 0; mt < 4; mt++)
#pragma unroll
            for (int nt = 0; nt < NT; nt++)
                acc[mt][nt] = __builtin_amdgcn_mfma_f32_16x16x32_bf16(af[mt], bf[nt], acc[mt][nt], 0, 0, 0);
    }

#pragma unroll
    for (int nt = 0; nt < NT; nt++) {
        int col = n0 + wn * (BN / 2) + nt * 16 + l15;
        float bs = bias[col];
#pragma unroll
        for (int mt = 0; mt < 4; mt++) {
            int row = m0 + wm * 64 + mt * 16 + quad * 4;
#pragma unroll
            for (int r = 0; r < 4; r++) {
                float v = acc[mt][nt][r] + bs;
                if (EPI == 0) {
                    ((float*)Cout)[(size_t)(row + r) * N + col] = v;
                } else {
                    int rr = row + r;
                    int bi = rr >> 10, ni = rr & 1023;
                    int h = col >> 9, d = col & 511;
                    int bh = bi * 8 + h;
                    ((u16*)Cout)[(((size_t)(bh * 64 + (d >> 3))) * 1024 + ni) * 8 + (d & 7)] = f2bf(v);
                }
            }
        }
    }
}

// ---------------------------------------------------------------------------
// Flash attention v2.  grid = 32 bh * 16 qblocks = 512 blocks, block = 256 (4 waves).
// q-tile 64 per block; m-chunk 32; 128 iters; no-max online softmax (|s|<~4).
// S-phase: wave (wq=w>>1, wm=w&1) computes S[wq*32..+32, wm*16..+16].
//   A (Q) from registers (kc 0-3) + global K-major layout Qatt2 (kc 4-15).
//   B (K) from LDS Kc, staged via global_load_lds with XOR-swizzled 16B groups.
// PV-phase: wave w owns d-slice [w*128, w*128+128): O[64q,128d] = 4x8 tiles.
//   A (P) from LDS (pad-36 stride), B (V^T) direct from global (no LDS reuse).
__global__ __launch_bounds__(256, 2) void flash_kernel(const u16* __restrict__ Qatt2,
                                                       const u16* __restrict__ Kb,
                                                       const u16* __restrict__ Vtb,
                                                       u16* __restrict__ rv) {
    __shared__ __align__(16) u16 Kc[32 * 512];   // 32 KB, swizzled: (row, physgrp)
    __shared__ __align__(16) u16 P[64 * 36];     // 4.5 KB, stride 36
    __shared__ float dn[2][64];                  // denominator partials per wm

    int tid = threadIdx.x;
    int w = tid >> 6, lane = tid & 63, l15 = lane & 15, quad = lane >> 4;
    int wq = w >> 1, wm = w & 1;
    int bh = blockIdx.x >> 4, qb = blockIdx.x & 15;
    int q0 = qb * 64;
    const float sc = 0.06375871826463886f; // log2(e)/sqrt(512)

    // Q fragment base: Qatt2[((bh*64 + kgrp)*1024 + n)*8]
    const u16* qbase = Qatt2 + ((size_t)bh * 64) * 1024 * 8;
    int nrow0 = q0 + wq * 32 + l15;      // tile t adds +16

    // register-pinned A fragments for kc 0..3
    short8 qf[2][4];
#pragma unroll
    for (int kc = 0; kc < 4; kc++) {
#pragma unroll
        for (int t = 0; t < 2; t++)
            qf[t][kc] = *(const short8*)(qbase + ((size_t)(kc * 4 + quad) * 1024 + nrow0 + t * 16) * 8);
    }

    f32x4 acc[4][8];
#pragma unroll
    for (int i = 0; i < 4; i++)
#pragma unroll
        for (int j = 0; j < 8; j++) acc[i][j] = (f32x4)(0.0f);
    float dp[2][4] = {{0.f, 0.f, 0.f, 0.f}, {0.f, 0.f, 0.f, 0.f}};

    int mr = wm * 16 + l15;       // S-phase B row in K-chunk
    int swz = mr & 7;

    for (int m0 = 0; m0 < 4096; m0 += 32) {
        __syncthreads();  // prev S done reading Kc, prev PV done reading P
        // ---- stage K-chunk [32m][512k] via async DMA, swizzled 16B groups ----
#pragma unroll
        for (int o = 0; o < 8; o++) {
            int row = w * 8 + o;
            const u16* gsrc = Kb + (size_t)(m0 + row) * 512 + (lane ^ (row & 7)) * 8;
            GLD_LDS16(gsrc, &Kc[row * 512]);
        }
        __syncthreads();  // staging visible (barrier drains vmcnt)

        // ---- S-phase: S[32q x 16m] per wave ----
        f32x4 s0 = (f32x4)(0.0f), s1 = (f32x4)(0.0f);
#pragma unroll
        for (int kc = 0; kc < 16; kc++) {
            short8 a0, a1;
            if (kc < 4) {
                a0 = qf[0][kc]; a1 = qf[1][kc];
            } else {
                const u16* qp = qbase + ((size_t)(kc * 4 + quad) * 1024 + nrow0) * 8;
                a0 = *(const short8*)(qp);
                a1 = *(const short8*)(qp + 16 * 8);
            }
            int phys = (kc * 4 + quad) ^ swz;
            short8 b = *(const short8*)&Kc[mr * 512 + phys * 8];
            s0 = __builtin_amdgcn_mfma_f32_16x16x32_bf16(a0, b, s0, 0, 0, 0);
            s1 = __builtin_amdgcn_mfma_f32_16x16x32_bf16(a1, b, s1, 0, 0, 0);
        }
        // ---- exp + denominator partials + P to LDS ----
#pragma unroll
        for (int r = 0; r < 4; r++) {
            float p0 = exp2f(s0[r] * sc);
            float p1 = exp2f(s1[r] * sc);
            dp[0][r] += p0;
            dp[1][r] += p1;
            P[(wq * 32 + quad * 4 + r) * 36 + wm * 16 + l15] = f2bf(p0);
            P[(wq * 32 + 16 + quad * 4 + r) * 36 + wm * 16 + l15] = f2bf(p1);
        }
        __syncthreads();  // P visible to all waves

        // ---- PV-phase: O[64q, 128d] per wave, d-slice = w*128 ----
        short8 ap[4];
#pragma unroll
        for (int qt = 0; qt < 4; qt++)
            ap[qt] = *(const short8*)&P[(qt * 16 + l15) * 36 + quad * 8];
#pragma unroll
        for (int dt = 0; dt < 8; dt++) {
            short8 bv = *(const short8*)(Vtb + (size_t)(w * 128 + dt * 16 + l15) * 4096 + m0 + quad * 8);
#pragma unroll
            for (int qt = 0; qt < 4; qt++)
                acc[qt][dt] = __builtin_amdgcn_mfma_f32_16x16x32_bf16(ap[qt], bv, acc[qt][dt], 0, 0, 0);
        }
    }

    // ---- denominator: reduce over the 16 m-lanes, combine wm partials ----
#pragma unroll
    for (int t = 0; t < 2; t++)
#pragma unroll
        for (int r = 0; r < 4; r++) {
            float d = dp[t][r];
            d += __shfl_xor(d, 1); d += __shfl_xor(d, 2);
            d += __shfl_xor(d, 4); d += __shfl_xor(d, 8);
            dp[t][r] = d;
        }
    if (l15 == 0) {
#pragma unroll
        for (int t = 0; t < 2; t++)
#pragma unroll
            for (int r = 0; r < 4; r++)
                dn[wm][wq * 32 + t * 16 + quad * 4 + r] = dp[t][r];
    }
    __syncthreads();

    // ---- epilogue: normalize + write rv[b, n, h*512 + d] ----
    int b = bh >> 3, h = bh & 7;
#pragma unroll
    for (int qt = 0; qt < 4; qt++) {
#pragma unroll
        for (int r = 0; r < 4; r++) {
            int qrow = qt * 16 + quad * 4 + r;
            float inv = 1.0f / (dn[0][qrow] + dn[1][qrow]);
            size_t base = ((size_t)(b * 1024 + q0 + qrow)) * 4096 + h * 512 + w * 128 + l15;
#pragma unroll
            for (int dt = 0; dt < 8; dt++)
                rv[base + dt * 16] = f2bf(acc[qt][dt][r] * inv);
        }
    }
}

// ---------------------------------------------------------------------------
// sims argmax (fp32 — bf16 would misrank slots). mnT is [512 k][4096 m].
// grid = 256 blocks = (64 write-groups of 16) x (4 m-quarters). block = 256.
__global__ __launch_bounds__(256) void sims_argmax_kernel(const float* __restrict__ wk,
                                                          const float* __restrict__ mnT,
                                                          u64* __restrict__ amax) {
    __shared__ float wkl[16][512];
    int tid = threadIdx.x;
    int bw = blockIdx.x & 63, mq = blockIdx.x >> 6;
    int w0 = bw * 16, m0 = mq * 1024;
    for (int i = tid; i < 16 * 512; i += 256) wkl[i >> 9][i & 511] = wk[(size_t)w0 * 512 + i];
    __syncthreads();
    int mbase = m0 + tid * 4;
    float accv[16][4];
#pragma unroll
    for (int i = 0; i < 16; i++)
#pragma unroll
        for (int j = 0; j < 4; j++) accv[i][j] = 0.f;
    for (int k = 0; k < 512; k++) {
        float4 v = *(const float4*)&mnT[(size_t)k * 4096 + mbase];
#pragma unroll
        for (int wi = 0; wi < 16; wi++) {
            float s = wkl[wi][k];
            accv[wi][0] += s * v.x; accv[wi][1] += s * v.y;
            accv[wi][2] += s * v.z; accv[wi][3] += s * v.w;
        }
    }
#pragma unroll
    for (int wi = 0; wi < 16; wi++) {
        u64 best = 0;
#pragma unroll
        for (int j = 0; j < 4; j++) {
            u32 bb = __float_as_uint(accv[wi][j]);
            bb = (bb & 0x80000000u) ? ~bb : (bb | 0x80000000u);
            u64 key = ((u64)bb << 32) | (u32)(4095 - (mbase + j)); // ties -> smaller m wins
            best = best > key ? best : key;
        }
        atomicMax(&amax[w0 + wi], best);
    }
}

// ---------------------------------------------------------------------------
// decode idx from amax keys, build per-slot chains (next[], heads[], count).
// single block of 1024 threads.
__global__ void chains_build_kernel(const u64* __restrict__ amax, int* __restrict__ idx,
                                    int* __restrict__ nxt, int* __restrict__ heads,
                                    int* __restrict__ count) {
    int i = threadIdx.x;
    idx[i] = 4095 - (int)(u32)(amax[i] & 0xFFFFFFFFull);
    __syncthreads();
    int my = idx[i];
    int nx = -1;
    for (int j = i + 1; j < 1024; j++)
        if (idx[j] == my) { nx = j; break; }
    nxt[i] = nx;
    bool head = true;
    for (int j = 0; j < i; j++)
        if (idx[j] == my) { head = false; break; }
    if (head) {
        int p = atomicAdd(count, 1);
        heads[p] = i;
    }
}

// ---------------------------------------------------------------------------
// G1[i][j] = write_keys[i] . Wg[0:512, j] + bg[j]   (fp32). 8 rows/block, grid=128.
__global__ __launch_bounds__(256) void g1_gemm_kernel(const float* __restrict__ wk,
                                                      const float* __restrict__ Wg,
                                                      const float* __restrict__ bg,
                                                      float* __restrict__ G1) {
    __shared__ float wkl[8][512];
    int tid = threadIdx.x;
    int i0 = blockIdx.x * 8;
    for (int i = tid; i < 8 * 512; i += 256) wkl[i >> 9][i & 511] = wk[(size_t)i0 * 512 + i];
    __syncthreads();
    float a0[8], a1[8];
#pragma unroll
    for (int i = 0; i < 8; i++) { a0[i] = 0.f; a1[i] = 0.f; }
    for (int c = 0; c < 512; c++) {
        float w0 = Wg[(size_t)c * 512 + tid];
        float w1 = Wg[(size_t)c * 512 + tid + 256];
#pragma unroll
        for (int ii = 0; ii < 8; ii++) {
            float s = wkl[ii][c];
            a0[ii] += s * w0; a1[ii] += s * w1;
        }
    }
    float b0 = bg[tid], b1 = bg[tid + 256];
#pragma unroll
    for (int ii = 0; ii < 8; ii++) {
        G1[(size_t)(i0 + ii) * 512 + tid] = a0[ii] + b0;
        G1[(size_t)(i0 + ii) * 512 + tid + 256] = a1[ii] + b1;
    }
}

// ---------------------------------------------------------------------------
// Apply per-slot chains sequentially (fp32). block = 256 threads per chain.
__global__ __launch_bounds__(256) void chain_apply_kernel(const int* __restrict__ heads,
                                                          const int* __restrict__ count,
                                                          const int* __restrict__ idx,
                                                          const int* __restrict__ nxt,
                                                          const float* __restrict__ G1,
                                                          const float* __restrict__ Wg,
                                                          const float* __restrict__ wk,
                                                          const float* __restrict__ wv,
                                                          const float* __restrict__ mk,
                                                          const float* __restrict__ mv,
                                                          float* __restrict__ outK,
                                                          float* __restrict__ outV) {
    int b = blockIdx.x;
    if (b >= *count) return;
    int i = heads[b];
    int s = idx[i];
    int tid = threadIdx.x;
    __shared__ float V[512];
    V[tid] = mv[(size_t)s * 512 + tid];
    V[tid + 256] = mv[(size_t)s * 512 + tid + 256];
    float k0 = mk[(size_t)s * 512 + tid], k1 = mk[(size_t)s * 512 + tid + 256];
    __syncthreads();
    while (i >= 0) {
        float a0 = G1[(size_t)i * 512 + tid], a1 = G1[(size_t)i * 512 + tid + 256];
        for (int c = 0; c < 512; c++) {
            float vc = V[c];
            a0 += vc * Wg[(size_t)(512 + c) * 512 + tid];
            a1 += vc * Wg[(size_t)(512 + c) * 512 + tid + 256];
        }
        float g0 = 1.f / (1.f + __expf(-a0));
        float g1 = 1.f / (1.f + __expf(-a1));
        __syncthreads(); // everyone finished reading V
        k0 = g0 * wk[(size_t)i * 512 + tid] + (1.f - g0) * k0;
        k1 = g1 * wk[(size_t)i * 512 + tid + 256] + (1.f - g1) * k1;
        V[tid] = g0 * wv[(size_t)i * 512 + tid] + (1.f - g0) * V[tid];
        V[tid + 256] = g1 * wv[(size_t)i * 512 + tid + 256] + (1.f - g1) * V[tid + 256];
        __syncthreads();
        i = nxt[i];
    }
    outK[(size_t)s * 512 + tid] = k0;
    outK[(size_t)s * 512 + tid + 256] = k1;
    outV[(size_t)s * 512 + tid] = V[tid];
    outV[(size_t)s * 512 + tid + 256] = V[tid + 256];
}

// ---------------------------------------------------------------------------
extern "C" void kernel_launch(void* const* d_in, const int* in_sizes, int n_in,
                              void* d_out, int out_size, void* d_ws, size_t ws_size,
                              hipStream_t stream) {
    const float* queries = (const float*)d_in[0]; // [4,1024,512]
    const float* wkeys   = (const float*)d_in[1]; // [1024,512]
    const float* wvals   = (const float*)d_in[2]; // [1024,512]
    const float* mkeys   = (const float*)d_in[3]; // [4096,512]
    const float* mvals   = (const float*)d_in[4]; // [4096,512]
    const float* Wq      = (const float*)d_in[5]; // [512,4096]
    const float* bq      = (const float*)d_in[6]; // [4096]
    const float* Wvp     = (const float*)d_in[7]; // [4096,512]
    const float* bvp     = (const float*)d_in[8]; // [512]
    const float* Wg      = (const float*)d_in[9]; // [1024,512]
    const float* bg      = (const float*)d_in[10];// [512]

    float* out_read = (float*)d_out;              // [4,1024,512]
    float* out_k = out_read + (size_t)4 * 1024 * 512; // [4096,512]
    float* out_v = out_k + (size_t)4096 * 512;        // [4096,512]

    char* ws = (char*)d_ws;
    const size_t MB = 1024 * 1024;
    u16* Qbf  = (u16*)(ws);            // 4 MB   queries bf16 [4096,512]
    u16* WqT  = (u16*)(ws + 4 * MB);   // 4 MB   Wq^T bf16 [4096,512]
    u16* Qatt2= (u16*)(ws + 8 * MB);   // 32 MB  q bf16, K-major [(b,h),kgrp,n,8]
    u16* Kb   = (u16*)(ws + 40 * MB);  // 4 MB   mem_keys bf16 [4096,512]
    u16* Vtb  = (u16*)(ws + 44 * MB);  // 4 MB   mem_values^T bf16 [512,4096]
    u16* rv   = (u16*)(ws + 48 * MB);  // 32 MB  attention out bf16 [4096, 4096]
    u16* WvpT = (u16*)(ws + 80 * MB);  // 4 MB   Wvp^T bf16 [512,4096]
    float* mn  = (float*)(ws + 84 * MB); // 8 MB normalized mem_keys [4096,512]
    float* G1  = (float*)(ws + 92 * MB); // 2 MB gate pre from write_keys [1024,512]
    float* mnT = (float*)(ws + 94 * MB); // 8 MB normalized keys transposed [512,4096]
    char* meta = ws + 102 * MB;
    u64* amax  = (u64*)(meta);                 // 8 KB
    int* count = (int*)(meta + 8192);          // 4 B
    int* idx   = (int*)(meta + 8192 + 256);    // 4 KB
    int* nxt   = (int*)(meta + 8192 + 256 + 4096);  // 4 KB
    int* heads = (int*)(meta + 8192 + 256 + 8192);  // 4 KB
    (void)in_sizes; (void)n_in; (void)out_size; (void)ws_size;

    // new_keys / new_values start as copies of mem_keys / mem_values
    hipMemcpyAsync(out_k, mkeys, (size_t)4096 * 512 * 4, hipMemcpyDeviceToDevice, stream);
    hipMemcpyAsync(out_v, mvals, (size_t)4096 * 512 * 4, hipMemcpyDeviceToDevice, stream);
    hipMemsetAsync(amax, 0, 8192 + 256, stream); // amax keys + count

    // ---- prep casts / transposes ----
    cast_bf16_kernel<<<2048, 256, 0, stream>>>(queries, Qbf);
    cast_transpose_kernel<<<dim3(4096 / 32, 512 / 32), 256, 0, stream>>>(Wq, WqT, 512, 4096);
    cast_transpose_kernel<<<dim3(512 / 32, 4096 / 32), 256, 0, stream>>>(Wvp, WvpT, 4096, 512);
    cast_transpose_kernel<<<dim3(512 / 32, 4096 / 32), 256, 0, stream>>>(mvals, Vtb, 4096, 512);
    key_prep_kernel<<<4096, 256, 0, stream>>>(mkeys, mn, Kb);
    transpose_f32_kernel<<<dim3(512 / 32, 4096 / 32), 256, 0, stream>>>(mn, mnT, 4096, 512);

    // ---- read path ----
    gemm_bt_kernel<128, 1><<<dim3(32, 32), 256, 0, stream>>>(Qbf, WqT, bq, (void*)Qatt2, 4096, 4096, 512);
    flash_kernel<<<512, 256, 0, stream>>>(Qatt2, Kb, Vtb, rv);
    gemm_bt_kernel<64, 0><<<dim3(8, 32), 256, 0, stream>>>(rv, WvpT, bvp, (void*)out_read, 4096, 512, 4096);

    // ---- write path (fp32) ----
    sims_argmax_kernel<<<256, 256, 0, stream>>>(wkeys, mnT, amax);
    chains_build_kernel<<<1, 1024, 0, stream>>>(amax, idx, nxt, heads, count);
    g1_gemm_kernel<<<128, 256, 0, stream>>>(wkeys, Wg, bg, G1);
    chain_apply_kernel<<<1024, 256, 0, stream>>>(heads, count, idx, nxt, G1, Wg,
                                                 wkeys, wvals, mkeys, mvals, out_k, out_v);
}

// Round 3
// 1094.966 us; speedup vs baseline: 1.7223x; 1.7223x over previous
//
#include <hip/hip_runtime.h>
#include <cstdint>
#include <cstddef>

typedef __attribute__((ext_vector_type(8))) short short8;
typedef __attribute__((ext_vector_type(4))) float f32x4;
typedef unsigned short u16;
typedef unsigned int u32;
typedef unsigned long long u64;

__device__ __forceinline__ u16 f2bf(float f) {
    u32 u = __float_as_uint(f);
    u = (u + 0x7FFFu + ((u >> 16) & 1u)) >> 16;
    return (u16)u;
}

// ---------------------------------------------------------------------------
// Elementwise cast fp32 -> bf16 (vectorized x4). n must be multiple of 4.
__global__ void cast_bf16_kernel(const float* __restrict__ src, u16* __restrict__ dst) {
    int i = blockIdx.x * 256 + threadIdx.x;
    float4 v = *((const float4*)src + i);
    ushort4 r;
    r.x = f2bf(v.x); r.y = f2bf(v.y); r.z = f2bf(v.z); r.w = f2bf(v.w);
    *((ushort4*)dst + i) = r;
}

// ---------------------------------------------------------------------------
// Tiled transpose: src fp32 [R][C] -> dst bf16 [C][R]. grid=(C/32, R/32), block=256.
__global__ void cast_transpose_kernel(const float* __restrict__ src, u16* __restrict__ dst,
                                      int R, int C) {
    __shared__ float tile[32][33];
    int tx = threadIdx.x & 31, ty = threadIdx.x >> 5;
    int c0 = blockIdx.x * 32, r0 = blockIdx.y * 32;
#pragma unroll
    for (int j = 0; j < 4; j++)
        tile[ty + 8 * j][tx] = src[(size_t)(r0 + ty + 8 * j) * C + c0 + tx];
    __syncthreads();
#pragma unroll
    for (int j = 0; j < 4; j++)
        dst[(size_t)(c0 + ty + 8 * j) * R + r0 + tx] = f2bf(tile[tx][ty + 8 * j]);
}

// Tiled transpose: src fp32 [R][C] -> dst fp32 [C][R].
__global__ void transpose_f32_kernel(const float* __restrict__ src, float* __restrict__ dst,
                                     int R, int C) {
    __shared__ float tile[32][33];
    int tx = threadIdx.x & 31, ty = threadIdx.x >> 5;
    int c0 = blockIdx.x * 32, r0 = blockIdx.y * 32;
#pragma unroll
    for (int j = 0; j < 4; j++)
        tile[ty + 8 * j][tx] = src[(size_t)(r0 + ty + 8 * j) * C + c0 + tx];
    __syncthreads();
#pragma unroll
    for (int j = 0; j < 4; j++)
        dst[(size_t)(c0 + ty + 8 * j) * R + r0 + tx] = tile[tx][ty + 8 * j];
}

// ---------------------------------------------------------------------------
// mem_keys -> mn (fp32 row-normalized, for argmax) and Kb (bf16 raw, for attention)
__global__ __launch_bounds__(256) void key_prep_kernel(const float* __restrict__ mk,
                                                       float* __restrict__ mn,
                                                       u16* __restrict__ Kb) {
    int row = blockIdx.x, tid = threadIdx.x;
    const float* src = mk + (size_t)row * 512;
    float x0 = src[tid], x1 = src[tid + 256];
    float ss = x0 * x0 + x1 * x1;
#pragma unroll
    for (int m = 1; m < 64; m <<= 1) ss += __shfl_xor(ss, m);
    __shared__ float sred[4];
    if ((tid & 63) == 0) sred[tid >> 6] = ss;
    __syncthreads();
    float tot = sred[0] + sred[1] + sred[2] + sred[3];
    float inv = 1.0f / fmaxf(sqrtf(tot), 1e-8f);
    mn[(size_t)row * 512 + tid] = x0 * inv;
    mn[(size_t)row * 512 + tid + 256] = x1 * inv;
    Kb[(size_t)row * 512 + tid] = f2bf(x0);
    Kb[(size_t)row * 512 + tid + 256] = f2bf(x1);
}

// ---------------------------------------------------------------------------
// GEMM: C[M,N] = A[M,K] * Bt[N,K]^T + bias[N].  bf16 inputs, fp32 accumulate.
// BM=128 fixed, BN template (128 or 64). block=256 (4 waves, 2x2 quadrants).
// EPI==0: write fp32 C row-major [M,N].
// EPI==1: q-proj permute: row=(b*1024+n), col=(h*512+d) -> Qatt bf16 [((b*8+h)*1024+n)*512+d]
template <int BN, int EPI>
__global__ __launch_bounds__(256, 2) void gemm_bt_kernel(const u16* __restrict__ A,
                                                         const u16* __restrict__ Bt,
                                                         const float* __restrict__ bias,
                                                         void* __restrict__ Cout,
                                                         int M, int N, int K) {
    constexpr int NT = BN / 32;
    __shared__ __align__(16) u16 A_lds[128 * 40];
    __shared__ __align__(16) u16 B_lds[BN * 40];
    int tid = threadIdx.x;
    int w = tid >> 6, lane = tid & 63, l15 = lane & 15, quad = lane >> 4;
    int wm = w >> 1, wn = w & 1;
    int n0 = blockIdx.x * BN, m0 = blockIdx.y * 128;

    f32x4 acc[4][NT];
#pragma unroll
    for (int i = 0; i < 4; i++)
#pragma unroll
        for (int j = 0; j < NT; j++) acc[i][j] = (f32x4)(0.0f);

    for (int kt = 0; kt < K; kt += 32) {
        __syncthreads();
#pragma unroll
        for (int i = 0; i < 2; i++) {
            int c = i * 256 + tid;
            int r = c >> 2, col = c & 3;
            *(uint4*)&A_lds[r * 40 + col * 8] =
                *(const uint4*)&A[(size_t)(m0 + r) * K + kt + col * 8];
        }
#pragma unroll
        for (int i = 0; i < BN / 64; i++) {
            int c = i * 256 + tid;
            int r = c >> 2, col = c & 3;
            *(uint4*)&B_lds[r * 40 + col * 8] =
                *(const uint4*)&Bt[(size_t)(n0 + r) * K + kt + col * 8];
        }
        __syncthreads();
        short8 af[4], bf[NT];
#pragma unroll
        for (int mt = 0; mt < 4; mt++)
            af[mt] = *(const short8*)&A_lds[(wm * 64 + mt * 16 + l15) * 40 + quad * 8];
#pragma unroll
        for (int nt = 0; nt < NT; nt++)
            bf[nt] = *(const short8*)&B_lds[(wn * (BN / 2) + nt * 16 + l15) * 40 + quad * 8];
#pragma unroll
        for (int mt = 0; mt < 4; mt++)
#pragma unroll
            for (int nt = 0; nt < NT; nt++)
                acc[mt][nt] = __builtin_amdgcn_mfma_f32_16x16x32_bf16(af[mt], bf[nt], acc[mt][nt], 0, 0, 0);
    }

#pragma unroll
    for (int nt = 0; nt < NT; nt++) {
        int col = n0 + wn * (BN / 2) + nt * 16 + l15;
        float bs = bias[col];
#pragma unroll
        for (int mt = 0; mt < 4; mt++) {
            int row = m0 + wm * 64 + mt * 16 + quad * 4;
#pragma unroll
            for (int r = 0; r < 4; r++) {
                float v = acc[mt][nt][r] + bs;
                if (EPI == 0) {
                    ((float*)Cout)[(size_t)(row + r) * N + col] = v;
                } else {
                    int rr = row + r;
                    int bi = rr >> 10, ni = rr & 1023;
                    int h = col >> 9, d = col & 511;
                    ((u16*)Cout)[(((size_t)((bi * 8 + h)) * 1024 + ni)) * 512 + d] = f2bf(v);
                }
            }
        }
    }
}

// ---------------------------------------------------------------------------
// S-pass: P[M,4096] = exp2(sc * A[M,512] * Kb[4096,512]^T), denom[row] += rowsum.
// m97 structure: BM=128, BN=128, K=512. grid=(32, M/128). A/denom pre-offset by bh0.
__global__ __launch_bounds__(256, 2) void s_exp_gemm_kernel(const u16* __restrict__ A,
                                                            const u16* __restrict__ Bt,
                                                            u16* __restrict__ P,
                                                            float* __restrict__ denom) {
    __shared__ __align__(16) u16 A_lds[128 * 40];
    __shared__ __align__(16) u16 B_lds[128 * 40];
    int tid = threadIdx.x;
    int w = tid >> 6, lane = tid & 63, l15 = lane & 15, quad = lane >> 4;
    int wm = w >> 1, wn = w & 1;
    int n0 = blockIdx.x * 128, m0 = blockIdx.y * 128;

    f32x4 acc[4][4];
#pragma unroll
    for (int i = 0; i < 4; i++)
#pragma unroll
        for (int j = 0; j < 4; j++) acc[i][j] = (f32x4)(0.0f);

    for (int kt = 0; kt < 512; kt += 32) {
        __syncthreads();
#pragma unroll
        for (int i = 0; i < 2; i++) {
            int c = i * 256 + tid;
            int r = c >> 2, col = c & 3;
            *(uint4*)&A_lds[r * 40 + col * 8] =
                *(const uint4*)&A[(size_t)(m0 + r) * 512 + kt + col * 8];
            *(uint4*)&B_lds[r * 40 + col * 8] =
                *(const uint4*)&Bt[(size_t)(n0 + r) * 512 + kt + col * 8];
        }
        __syncthreads();
        short8 af[4], bf[4];
#pragma unroll
        for (int mt = 0; mt < 4; mt++)
            af[mt] = *(const short8*)&A_lds[(wm * 64 + mt * 16 + l15) * 40 + quad * 8];
#pragma unroll
        for (int nt = 0; nt < 4; nt++)
            bf[nt] = *(const short8*)&B_lds[(wn * 64 + nt * 16 + l15) * 40 + quad * 8];
#pragma unroll
        for (int mt = 0; mt < 4; mt++)
#pragma unroll
            for (int nt = 0; nt < 4; nt++)
                acc[mt][nt] = __builtin_amdgcn_mfma_f32_16x16x32_bf16(af[mt], bf[nt], acc[mt][nt], 0, 0, 0);
    }

    const float sc = 0.06375871826463886f; // log2(e)/sqrt(512)
#pragma unroll
    for (int mt = 0; mt < 4; mt++) {
#pragma unroll
        for (int r = 0; r < 4; r++) {
            int row = m0 + wm * 64 + mt * 16 + quad * 4 + r;
            float rs = 0.f;
#pragma unroll
            for (int nt = 0; nt < 4; nt++) {
                int col = n0 + wn * 64 + nt * 16 + l15;
                float p = exp2f(acc[mt][nt][r] * sc);
                rs += p;
                P[(size_t)row * 4096 + col] = f2bf(p);
            }
            rs += __shfl_xor(rs, 1); rs += __shfl_xor(rs, 2);
            rs += __shfl_xor(rs, 4); rs += __shfl_xor(rs, 8);
            if (l15 == 0) atomicAdd(&denom[row], rs);
        }
    }
}

// ---------------------------------------------------------------------------
// PV-pass: rv = (P[M,4096] * Vtb[512,4096]^T) / denom, scattered to
// rv[b*1024+n, h*512+d] with global row gr = bh0*1024 + local row.
// BM=128, BN=128, K=4096. grid=(4, M/128). P/denom pre-offset by bh0.
__global__ __launch_bounds__(256, 2) void pv_gemm_kernel(const u16* __restrict__ A,
                                                         const u16* __restrict__ Bt,
                                                         const float* __restrict__ denom,
                                                         u16* __restrict__ rv,
                                                         int bh0) {
    __shared__ __align__(16) u16 A_lds[128 * 40];
    __shared__ __align__(16) u16 B_lds[128 * 40];
    int tid = threadIdx.x;
    int w = tid >> 6, lane = tid & 63, l15 = lane & 15, quad = lane >> 4;
    int wm = w >> 1, wn = w & 1;
    int n0 = blockIdx.x * 128, m0 = blockIdx.y * 128;

    f32x4 acc[4][4];
#pragma unroll
    for (int i = 0; i < 4; i++)
#pragma unroll
        for (int j = 0; j < 4; j++) acc[i][j] = (f32x4)(0.0f);

    for (int kt = 0; kt < 4096; kt += 32) {
        __syncthreads();
#pragma unroll
        for (int i = 0; i < 2; i++) {
            int c = i * 256 + tid;
            int r = c >> 2, col = c & 3;
            *(uint4*)&A_lds[r * 40 + col * 8] =
                *(const uint4*)&A[(size_t)(m0 + r) * 4096 + kt + col * 8];
            *(uint4*)&B_lds[r * 40 + col * 8] =
                *(const uint4*)&Bt[(size_t)(n0 + r) * 4096 + kt + col * 8];
        }
        __syncthreads();
        short8 af[4], bf[4];
#pragma unroll
        for (int mt = 0; mt < 4; mt++)
            af[mt] = *(const short8*)&A_lds[(wm * 64 + mt * 16 + l15) * 40 + quad * 8];
#pragma unroll
        for (int nt = 0; nt < 4; nt++)
            bf[nt] = *(const short8*)&B_lds[(wn * 64 + nt * 16 + l15) * 40 + quad * 8];
#pragma unroll
        for (int mt = 0; mt < 4; mt++)
#pragma unroll
            for (int nt = 0; nt < 4; nt++)
                acc[mt][nt] = __builtin_amdgcn_mfma_f32_16x16x32_bf16(af[mt], bf[nt], acc[mt][nt], 0, 0, 0);
    }

#pragma unroll
    for (int mt = 0; mt < 4; mt++) {
#pragma unroll
        for (int r = 0; r < 4; r++) {
            int lr = m0 + wm * 64 + mt * 16 + quad * 4 + r;
            int gr = bh0 * 1024 + lr;
            float inv = 1.0f / denom[lr];
            int b = gr >> 13, h = (gr >> 10) & 7, n = gr & 1023;
            size_t base = ((size_t)(b * 1024 + n)) * 4096 + h * 512;
#pragma unroll
            for (int nt = 0; nt < 4; nt++) {
                int col = n0 + wn * 64 + nt * 16 + l15;
                rv[base + col] = f2bf(acc[mt][nt][r] * inv);
            }
        }
    }
}

// ---------------------------------------------------------------------------
// sims argmax (fp32 — bf16 would misrank slots). mnT is [512 k][4096 m].
// grid = 256 blocks = (64 write-groups of 16) x (4 m-quarters). block = 256.
__global__ __launch_bounds__(256) void sims_argmax_kernel(const float* __restrict__ wk,
                                                          const float* __restrict__ mnT,
                                                          u64* __restrict__ amax) {
    __shared__ float wkl[16][512];
    int tid = threadIdx.x;
    int bw = blockIdx.x & 63, mq = blockIdx.x >> 6;
    int w0 = bw * 16, m0 = mq * 1024;
    for (int i = tid; i < 16 * 512; i += 256) wkl[i >> 9][i & 511] = wk[(size_t)w0 * 512 + i];
    __syncthreads();
    int mbase = m0 + tid * 4;
    float accv[16][4];
#pragma unroll
    for (int i = 0; i < 16; i++)
#pragma unroll
        for (int j = 0; j < 4; j++) accv[i][j] = 0.f;
    for (int k = 0; k < 512; k++) {
        float4 v = *(const float4*)&mnT[(size_t)k * 4096 + mbase];
#pragma unroll
        for (int wi = 0; wi < 16; wi++) {
            float s = wkl[wi][k];
            accv[wi][0] += s * v.x; accv[wi][1] += s * v.y;
            accv[wi][2] += s * v.z; accv[wi][3] += s * v.w;
        }
    }
#pragma unroll
    for (int wi = 0; wi < 16; wi++) {
        u64 best = 0;
#pragma unroll
        for (int j = 0; j < 4; j++) {
            u32 bb = __float_as_uint(accv[wi][j]);
            bb = (bb & 0x80000000u) ? ~bb : (bb | 0x80000000u);
            u64 key = ((u64)bb << 32) | (u32)(4095 - (mbase + j)); // ties -> smaller m wins
            best = best > key ? best : key;
        }
        atomicMax(&amax[w0 + wi], best);
    }
}

// ---------------------------------------------------------------------------
// decode idx from amax keys, build per-slot chains (next[], heads[], count).
// single block of 1024 threads.
__global__ void chains_build_kernel(const u64* __restrict__ amax, int* __restrict__ idx,
                                    int* __restrict__ nxt, int* __restrict__ heads,
                                    int* __restrict__ count) {
    int i = threadIdx.x;
    idx[i] = 4095 - (int)(u32)(amax[i] & 0xFFFFFFFFull);
    __syncthreads();
    int my = idx[i];
    int nx = -1;
    for (int j = i + 1; j < 1024; j++)
        if (idx[j] == my) { nx = j; break; }
    nxt[i] = nx;
    bool head = true;
    for (int j = 0; j < i; j++)
        if (idx[j] == my) { head = false; break; }
    if (head) {
        int p = atomicAdd(count, 1);
        heads[p] = i;
    }
}

// ---------------------------------------------------------------------------
// G1[i][j] = write_keys[i] . Wg[0:512, j] + bg[j]   (fp32). 8 rows/block, grid=128.
__global__ __launch_bounds__(256) void g1_gemm_kernel(const float* __restrict__ wk,
                                                      const float* __restrict__ Wg,
                                                      const float* __restrict__ bg,
                                                      float* __restrict__ G1) {
    __shared__ float wkl[8][512];
    int tid = threadIdx.x;
    int i0 = blockIdx.x * 8;
    for (int i = tid; i < 8 * 512; i += 256) wkl[i >> 9][i & 511] = wk[(size_t)i0 * 512 + i];
    __syncthreads();
    float a0[8], a1[8];
#pragma unroll
    for (int i = 0; i < 8; i++) { a0[i] = 0.f; a1[i] = 0.f; }
    for (int c = 0; c < 512; c++) {
        float w0 = Wg[(size_t)c * 512 + tid];
        float w1 = Wg[(size_t)c * 512 + tid + 256];
#pragma unroll
        for (int ii = 0; ii < 8; ii++) {
            float s = wkl[ii][c];
            a0[ii] += s * w0; a1[ii] += s * w1;
        }
    }
    float b0 = bg[tid], b1 = bg[tid + 256];
#pragma unroll
    for (int ii = 0; ii < 8; ii++) {
        G1[(size_t)(i0 + ii) * 512 + tid] = a0[ii] + b0;
        G1[(size_t)(i0 + ii) * 512 + tid + 256] = a1[ii] + b1;
    }
}

// ---------------------------------------------------------------------------
// Apply per-slot chains sequentially (fp32). block = 256 threads per chain.
__global__ __launch_bounds__(256) void chain_apply_kernel(const int* __restrict__ heads,
                                                          const int* __restrict__ count,
                                                          const int* __restrict__ idx,
                                                          const int* __restrict__ nxt,
                                                          const float* __restrict__ G1,
                                                          const float* __restrict__ Wg,
                                                          const float* __restrict__ wk,
                                                          const float* __restrict__ wv,
                                                          const float* __restrict__ mk,
                                                          const float* __restrict__ mv,
                                                          float* __restrict__ outK,
                                                          float* __restrict__ outV) {
    int b = blockIdx.x;
    if (b >= *count) return;
    int i = heads[b];
    int s = idx[i];
    int tid = threadIdx.x;
    __shared__ float V[512];
    V[tid] = mv[(size_t)s * 512 + tid];
    V[tid + 256] = mv[(size_t)s * 512 + tid + 256];
    float k0 = mk[(size_t)s * 512 + tid], k1 = mk[(size_t)s * 512 + tid + 256];
    __syncthreads();
    while (i >= 0) {
        float a0 = G1[(size_t)i * 512 + tid], a1 = G1[(size_t)i * 512 + tid + 256];
        for (int c = 0; c < 512; c++) {
            float vc = V[c];
            a0 += vc * Wg[(size_t)(512 + c) * 512 + tid];
            a1 += vc * Wg[(size_t)(512 + c) * 512 + tid + 256];
        }
        float g0 = 1.f / (1.f + __expf(-a0));
        float g1 = 1.f / (1.f + __expf(-a1));
        __syncthreads(); // everyone finished reading V
        k0 = g0 * wk[(size_t)i * 512 + tid] + (1.f - g0) * k0;
        k1 = g1 * wk[(size_t)i * 512 + tid + 256] + (1.f - g1) * k1;
        V[tid] = g0 * wv[(size_t)i * 512 + tid] + (1.f - g0) * V[tid];
        V[tid + 256] = g1 * wv[(size_t)i * 512 + tid + 256] + (1.f - g1) * V[tid + 256];
        __syncthreads();
        i = nxt[i];
    }
    outK[(size_t)s * 512 + tid] = k0;
    outK[(size_t)s * 512 + tid + 256] = k1;
    outV[(size_t)s * 512 + tid] = V[tid];
    outV[(size_t)s * 512 + tid + 256] = V[tid + 256];
}

// ---------------------------------------------------------------------------
extern "C" void kernel_launch(void* const* d_in, const int* in_sizes, int n_in,
                              void* d_out, int out_size, void* d_ws, size_t ws_size,
                              hipStream_t stream) {
    const float* queries = (const float*)d_in[0]; // [4,1024,512]
    const float* wkeys   = (const float*)d_in[1]; // [1024,512]
    const float* wvals   = (const float*)d_in[2]; // [1024,512]
    const float* mkeys   = (const float*)d_in[3]; // [4096,512]
    const float* mvals   = (const float*)d_in[4]; // [4096,512]
    const float* Wq      = (const float*)d_in[5]; // [512,4096]
    const float* bq      = (const float*)d_in[6]; // [4096]
    const float* Wvp     = (const float*)d_in[7]; // [4096,512]
    const float* bvp     = (const float*)d_in[8]; // [512]
    const float* Wg      = (const float*)d_in[9]; // [1024,512]
    const float* bg      = (const float*)d_in[10];// [512]

    float* out_read = (float*)d_out;              // [4,1024,512]
    float* out_k = out_read + (size_t)4 * 1024 * 512; // [4096,512]
    float* out_v = out_k + (size_t)4096 * 512;        // [4096,512]

    char* ws = (char*)d_ws;
    const size_t MB = 1024 * 1024;
    // region [0, 4MB): Qbf during prep/q-proj, then reused for meta + denom
    u16* Qbf  = (u16*)(ws);            // 4 MB   queries bf16 [4096,512]
    u16* WqT  = (u16*)(ws + 4 * MB);   // 4 MB   Wq^T bf16 [4096,512]
    u16* Qatt = (u16*)(ws + 8 * MB);   // 32 MB  q bf16 [(b,h),n,d] = [32768,512]
    u16* Kb   = (u16*)(ws + 40 * MB);  // 4 MB   mem_keys bf16 [4096,512]
    u16* Vtb  = (u16*)(ws + 44 * MB);  // 4 MB   mem_values^T bf16 [512,4096]
    u16* rv   = (u16*)(ws + 48 * MB);  // 32 MB  attention out bf16 [4096,4096]
    u16* WvpT = (u16*)(ws + 80 * MB);  // 4 MB   Wvp^T bf16 [512,4096]
    float* mn  = (float*)(ws + 84 * MB); // 8 MB normalized mem_keys [4096,512]
    float* G1  = (float*)(ws + 92 * MB); // 2 MB gate pre from write_keys [1024,512]
    float* mnT = (float*)(ws + 94 * MB); // 8 MB normalized keys transposed [512,4096]
    // meta + denom overlay the dead Qbf region (valid after q-proj completes)
    u64* amax   = (u64*)(ws);                   // 8 KB
    int* count  = (int*)(ws + 8192);            // 4 B
    int* idx    = (int*)(ws + 8192 + 256);      // 4 KB
    int* nxt    = (int*)(ws + 8192 + 256 + 4096);   // 4 KB
    int* heads  = (int*)(ws + 8192 + 256 + 8192);   // 4 KB
    float* denom = (float*)(ws + 32 * 1024);    // 128 KB [32768]
    // P overlays the dead mn/G1/mnT region (valid after chain_apply completes)
    u16* P = (u16*)(ws + 84 * MB);              // up to 256 MB [G*1024, 4096]
    (void)in_sizes; (void)n_in; (void)out_size;

    // chunk size over bh: P needs G*8MB starting at 84MB
    size_t avail = (ws_size > 84 * MB) ? ws_size - 84 * MB : 0;
    int G = 2; // proven-safe floor: 16 MB fits in [84MB, 100MB) (ws >= 102MB)
    for (int g = 32; g >= 2; g >>= 1)
        if ((size_t)g * 8 * MB <= avail) { G = g; break; }

    // new_keys / new_values start as copies of mem_keys / mem_values
    hipMemcpyAsync(out_k, mkeys, (size_t)4096 * 512 * 4, hipMemcpyDeviceToDevice, stream);
    hipMemcpyAsync(out_v, mvals, (size_t)4096 * 512 * 4, hipMemcpyDeviceToDevice, stream);

    // ---- prep casts / transposes ----
    cast_bf16_kernel<<<2048, 256, 0, stream>>>(queries, Qbf);
    cast_transpose_kernel<<<dim3(4096 / 32, 512 / 32), 256, 0, stream>>>(Wq, WqT, 512, 4096);
    cast_transpose_kernel<<<dim3(512 / 32, 4096 / 32), 256, 0, stream>>>(Wvp, WvpT, 4096, 512);
    cast_transpose_kernel<<<dim3(512 / 32, 4096 / 32), 256, 0, stream>>>(mvals, Vtb, 4096, 512);
    key_prep_kernel<<<4096, 256, 0, stream>>>(mkeys, mn, Kb);
    transpose_f32_kernel<<<dim3(512 / 32, 4096 / 32), 256, 0, stream>>>(mn, mnT, 4096, 512);

    // ---- q-proj (last user of Qbf/WqT) ----
    gemm_bt_kernel<128, 1><<<dim3(32, 32), 256, 0, stream>>>(Qbf, WqT, bq, (void*)Qatt, 4096, 4096, 512);

    // ---- write path (fp32), frees mn/G1/mnT for the P overlay afterwards ----
    hipMemsetAsync(ws, 0, 8192 + 256, stream);          // amax + count (Qbf now dead)
    hipMemsetAsync(denom, 0, 32768 * 4, stream);        // denom
    sims_argmax_kernel<<<256, 256, 0, stream>>>(wkeys, mnT, amax);
    chains_build_kernel<<<1, 1024, 0, stream>>>(amax, idx, nxt, heads, count);
    g1_gemm_kernel<<<128, 256, 0, stream>>>(wkeys, Wg, bg, G1);
    chain_apply_kernel<<<1024, 256, 0, stream>>>(heads, count, idx, nxt, G1, Wg,
                                                 wkeys, wvals, mkeys, mvals, out_k, out_v);

    // ---- attention as two GEMM passes, chunked over bh ----
    for (int bh0 = 0; bh0 < 32; bh0 += G) {
        const u16* Achunk = Qatt + (size_t)bh0 * 1024 * 512;
        float* dchunk = denom + bh0 * 1024;
        s_exp_gemm_kernel<<<dim3(32, G * 8), 256, 0, stream>>>(Achunk, Kb, P, dchunk);
        pv_gemm_kernel<<<dim3(4, G * 8), 256, 0, stream>>>(P, Vtb, dchunk, rv, bh0);
    }

    // ---- out-proj ----
    gemm_bt_kernel<64, 0><<<dim3(8, 32), 256, 0, stream>>>(rv, WvpT, bvp, (void*)out_read, 4096, 512, 4096);
}